// Round 5
// baseline (70.120 us; speedup 1.0000x reference)
//
#include <hip/hip_runtime.h>

#define B_     64
#define KDIM   2304
#define NCOL   1470
#define NCELL  3136   // 64 * 7 * 7
#define CPAD   1536
#define SPLITK 16
#define KCHUNK 144    // KDIM / SPLITK
#define NSTAGE 9      // KCHUNK / 16
#define XS     68     // sx row stride (writes 2-way free, reads broadcast)
#define WS     100    // sw col stride (writes 2-way free, reads conflict-free)

// ---------------------------------------------------------------------------
// GEMM: partial[kc][row][col] = sum_{k in chunk} x[row][k] * W[col][k]
// Grid (16 col-tiles of 96, 16 K-chunks) = 256 blocks = 1 per CU.
// Block 256. Micro-tile 8 rows x 3 cols (cols strided 32: conflict-free).
// Double-buffered LDS: register prefetch + ONE barrier per stage.
// ---------------------------------------------------------------------------
__global__ __launch_bounds__(256) void gemm_splitk(
    const float* __restrict__ x, const float* __restrict__ W,
    float* __restrict__ partial)
{
    __shared__ float sx[2][16 * XS];
    __shared__ float sw[2][16 * WS];

    const int t   = threadIdx.x;
    const int c0  = blockIdx.x * 96;
    const int k0  = blockIdx.y * KCHUNK;
    const int r8  = (t >> 5) << 3;   // 8-row group: 0,8,...,56
    const int cgi = t & 31;          // cols cgi + {0,32,64}
    const int kk0 = t & 15;
    const int g0  = t >> 4;          // 0..15

    float acc[8][3];
#pragma unroll
    for (int i = 0; i < 8; ++i)
#pragma unroll
        for (int j = 0; j < 3; ++j) acc[i][j] = 0.f;

    // clamped W row pointers for the 6 staged cols (garbage cols ignored later)
    const float* wp[6];
#pragma unroll
    for (int p = 0; p < 6; ++p) {
        int gc = c0 + p * 16 + g0;
        if (gc >= NCOL) gc = NCOL - 1;
        wp[p] = W + (size_t)gc * KDIM + kk0;
    }
    const float* xp = x + (size_t)g0 * 16 * 0 + kk0;   // x[row][k] accessed per-p below

    float xr[4], wr[6];
    {   // prologue: stage 0 -> regs -> buf0
        const int kb = k0;
#pragma unroll
        for (int p = 0; p < 4; ++p) xr[p] = x[(p * 16 + g0) * KDIM + kb + kk0];
#pragma unroll
        for (int p = 0; p < 6; ++p) wr[p] = wp[p][kb];
#pragma unroll
        for (int p = 0; p < 4; ++p) sx[0][kk0 * XS + p * 16 + g0] = xr[p];
#pragma unroll
        for (int p = 0; p < 6; ++p) sw[0][kk0 * WS + p * 16 + g0] = wr[p];
    }

    for (int s = 0; s < NSTAGE; ++s) {
        const int cb = s & 1;
        if (s + 1 < NSTAGE) {            // issue next-stage global loads now
            const int kb = k0 + ((s + 1) << 4);
#pragma unroll
            for (int p = 0; p < 4; ++p) xr[p] = x[(p * 16 + g0) * KDIM + kb + kk0];
#pragma unroll
            for (int p = 0; p < 6; ++p) wr[p] = wp[p][kb];
        }
        __syncthreads();                 // buf[cb] writes (prev iter) visible
        const float* cx = sx[cb];
        const float* cw = sw[cb];
#pragma unroll
        for (int kk = 0; kk < 16; ++kk) {
            const float4 a0 = *(const float4*)&cx[kk * XS + r8];
            const float4 a1 = *(const float4*)&cx[kk * XS + r8 + 4];
            const float w0 = cw[kk * WS + cgi];
            const float w1 = cw[kk * WS + cgi + 32];
            const float w2 = cw[kk * WS + cgi + 64];
            const float av[8] = {a0.x, a0.y, a0.z, a0.w, a1.x, a1.y, a1.z, a1.w};
#pragma unroll
            for (int i = 0; i < 8; ++i) {
                acc[i][0] = fmaf(av[i], w0, acc[i][0]);
                acc[i][1] = fmaf(av[i], w1, acc[i][1]);
                acc[i][2] = fmaf(av[i], w2, acc[i][2]);
            }
        }
        if (s + 1 < NSTAGE) {            // store prefetched regs -> other buffer
#pragma unroll
            for (int p = 0; p < 4; ++p) sx[cb ^ 1][kk0 * XS + p * 16 + g0] = xr[p];
#pragma unroll
            for (int p = 0; p < 6; ++p) sw[cb ^ 1][kk0 * WS + p * 16 + g0] = wr[p];
        }
    }

    float* pb = partial + (size_t)blockIdx.y * (B_ * CPAD) + c0 + cgi;
#pragma unroll
    for (int i = 0; i < 8; ++i)
#pragma unroll
        for (int p = 0; p < 3; ++p)
            pb[(size_t)(r8 + i) * CPAD + 32 * p] = acc[i][p];
}

// ---------------------------------------------------------------------------
// Fused split-K combine + bias + per-cell decode (8 cells per 256-thr block).
// ---------------------------------------------------------------------------
__global__ __launch_bounds__(256) void combine_prep(
    const float* __restrict__ partial, const float* __restrict__ bias,
    float* __restrict__ labels, float* __restrict__ boxes,
    float* __restrict__ scores, int* __restrict__ valid)
{
    __shared__ float sa[8][30];
    const int t    = threadIdx.x;
    const int base = blockIdx.x * 8;             // 392 * 8 == 3136 exactly

    if (t < 240) {
        const int n   = base + t / 30;
        const int col = t % 30;
        const int row = n / 49;                  // 1470/30 = 49 cells per batch-row
        const int cr  = (n % 49) * 30 + col;
        float s = 0.f;
#pragma unroll
        for (int k = 0; k < SPLITK; ++k)
            s += partial[(size_t)k * (B_ * CPAD) + (size_t)row * CPAD + cr];
        s += bias[cr];
        sa[t / 30][col] = s;
        if (col >= 10) labels[(size_t)n * 20 + (col - 10)] = s;
    }
    __syncthreads();

    if (t < 8) {
        const int n = base + t;
        const float* a = sa[t];
        float mv = a[10]; int mi = 0;
#pragma unroll
        for (int j = 1; j < 20; ++j) {
            float v = a[10 + j];
            if (v > mv) { mv = v; mi = j; }      // strict > => first-index tie-break
        }
        const float lp = (float)mi;
        const int gx = n % 7, gy = (n / 7) % 7;
        const float cw = 1.0f / 7.0f;
        const float nx = (float)gx * cw, ny = (float)gy * cw;
#pragma unroll
        for (int sl = 0; sl < 2; ++sl) {
            const int off = 5 * sl;
            const float bx0 = a[off], bx1 = a[off + 1];
            const float w_ = a[off + 2], h_ = a[off + 3];
            const float sc = a[off + 5];         // faithful port quirk: off+5
            const float cx = bx0 * cw + nx, cy = bx1 * cw + ny;
            const float X1 = cx - 0.5f * w_, Y1 = cy - 0.5f * h_;
            const float X2 = cx + 0.5f * w_, Y2 = cy + 0.5f * h_;
            const int m = sl * NCELL + n;
            boxes[m * 4 + 0] = X1 - 0.5f * X2;
            boxes[m * 4 + 1] = Y1 - 0.5f * Y2;
            boxes[m * 4 + 2] = X1 + 0.5f * X2;
            boxes[m * 4 + 3] = Y1 + 0.5f * Y2;
            scores[m] = sc;
            valid[m] = (sc * lp > 0.5f) ? 1 : 0;
        }
    }
}

// ---------------------------------------------------------------------------
// Fused inverted-greedy NMS + output pack. One 1024-thread block per slot.
// All NMS state in LDS (~91 KB); pack reads boxes/scores/keep from LDS and
// labels from L2, writes the slot's 3136x25 output directly.
// ---------------------------------------------------------------------------
__global__ __launch_bounds__(1024) void nms_pack(
    const float* __restrict__ boxes, const float* __restrict__ scores,
    const int* __restrict__ valid, const float* __restrict__ labels,
    float* __restrict__ out)
{
    __shared__ float bx1[NCELL], by1[NCELL], bx2[NCELL], by2[NCELL];
    __shared__ float ssc[NCELL];
    __shared__ int   lstA[NCELL], lstB[NCELL];
    __shared__ unsigned char kp[NCELL];
    __shared__ float rv[16];
    __shared__ int   ri[16];
    __shared__ int   cA, cB, spick;

    const int slot = blockIdx.x;
    const int base = slot * NCELL;
    const int t = threadIdx.x;

    if (t == 0) { cA = 0; cB = 0; }
    __syncthreads();
    for (int n = t; n < NCELL; n += 1024) {
        const float4 bb = *(const float4*)&boxes[(size_t)(base + n) * 4];
        bx1[n] = bb.x; by1[n] = bb.y; bx2[n] = bb.z; by2[n] = bb.w;
        ssc[n] = scores[base + n];
        kp[n] = 0;
        if (valid[base + n]) { int p = atomicAdd(&cA, 1); lstA[p] = n; }
    }
    __syncthreads();

    int* cur = lstA; int* nxt = lstB;
    int curIsA = 1;
    for (;;) {
        const int cnt = curIsA ? cA : cB;

        // ---- argmax over alive (first/min index wins ties) ----
        float bv = -1e30f; int bi = 0x7fffffff;
        for (int j = t; j < cnt; j += 1024) {
            const int n = cur[j];
            const float v = ssc[n];
            if (v > bv || (v == bv && n < bi)) { bv = v; bi = n; }
        }
#pragma unroll
        for (int o = 32; o > 0; o >>= 1) {
            const float ov = __shfl_down(bv, o);
            const int   oi = __shfl_down(bi, o);
            if (ov > bv || (ov == bv && oi < bi)) { bv = ov; bi = oi; }
        }
        if ((t & 63) == 0) { rv[t >> 6] = bv; ri[t >> 6] = bi; }
        __syncthreads();
        if (t == 0) {
            float v2 = rv[0]; int i2 = ri[0];
#pragma unroll
            for (int q = 1; q < 16; ++q)
                if (rv[q] > v2 || (rv[q] == v2 && ri[q] < i2)) { v2 = rv[q]; i2 = ri[q]; }
            spick = (v2 == -1e30f) ? -1 : i2;
            if (curIsA) cB = 0; else cA = 0;
        }
        __syncthreads();
        const int i = spick;
        if (i < 0) break;
        if (t == 0) kp[i] = 1;

        const float xi1 = bx1[i], yi1 = by1[i], xi2 = bx2[i], yi2 = by2[i];
        const float ai  = (xi2 - xi1) * (yi2 - yi1);

        int* nxtCnt = curIsA ? &cB : &cA;
        for (int j = t; j < cnt; j += 1024) {
            const int n = cur[j];
            const float x1 = bx1[n], y1 = by1[n], x2 = bx2[n], y2 = by2[n];
            const float an = (x2 - x1) * (y2 - y1);
            const float ix1 = fmaxf(x1, xi1), iy1 = fmaxf(y1, yi1);
            const float ix2 = fminf(x2, xi2), iy2 = fminf(y2, yi2);
            const float inter = fmaxf(ix2 - ix1, 0.f) * fmaxf(iy2 - iy1, 0.f);
            const float iou = inter / (ai + an - inter);   // IEEE divide, as reference
            if (iou >= 0.5f && n != i) { int p = atomicAdd(nxtCnt, 1); nxt[p] = n; }
        }
        __syncthreads();
        { int* tmp = cur; cur = nxt; nxt = tmp; }
        curIsA ^= 1;
    }

    // ---- pack this slot from LDS (+ labels from L2) ----
    float* os = out + (size_t)base * 25;
    for (int li = t; li < NCELL * 25; li += 1024) {
        const int n = li / 25;
        const int c = li % 25;
        const float k = (float)kp[n];
        float v;
        if (c < 4) {
            v = (c == 0 ? bx1[n] : c == 1 ? by1[n] : c == 2 ? bx2[n] : by2[n]) * 448.0f;
        } else if (c == 4) {
            v = ssc[n];
        } else {
            v = labels[(size_t)n * 20 + (c - 5)];
        }
        os[li] = v * k;
    }
}

// ---------------------------------------------------------------------------
extern "C" void kernel_launch(void* const* d_in, const int* in_sizes, int n_in,
                              void* d_out, int out_size, void* d_ws, size_t ws_size,
                              hipStream_t stream)
{
    const float* x = (const float*)d_in[0];
    const float* W = (const float*)d_in[1];
    const float* b = (const float*)d_in[2];
    float* out = (float*)d_out;

    float* ws      = (float*)d_ws;
    float* partial = ws;                                        // 16*64*1536
    float* labels  = partial + (size_t)SPLITK * B_ * CPAD;      // 3136*20
    float* boxes   = labels + (size_t)NCELL * 20;               // 3136*8
    float* scores  = boxes + (size_t)NCELL * 8;                 // 3136*2
    int*   valid   = (int*)(scores + (size_t)NCELL * 2);        // 3136*2

    hipLaunchKernelGGL(gemm_splitk, dim3(16, SPLITK), dim3(256), 0, stream,
                       x, W, partial);
    hipLaunchKernelGGL(combine_prep, dim3(NCELL / 8), dim3(256), 0, stream,
                       partial, b, labels, boxes, scores, valid);
    hipLaunchKernelGGL(nms_pack, dim3(2), dim3(1024), 0, stream,
                       boxes, scores, valid, labels, out);
}

// Round 6
// 50.169 us; speedup vs baseline: 1.3977x; 1.3977x over previous
//
#include <hip/hip_runtime.h>

#define B_     64
#define KDIM   2304
#define NCOL   1470
#define NCELL  3136   // 64 * 7 * 7
#define CPAD   1536
#define SPLITK 16
#define KCHUNK 144    // KDIM / SPLITK
#define NSTAGE 9      // KCHUNK / 16
#define XS     68     // sx row stride (writes 2-way free, reads broadcast)
#define WSD    100    // sw col stride (writes 2-way free, reads conflict-free)
#define NMS_T  256
#define QMAX   13     // ceil(NCELL / NMS_T)

// ---------------------------------------------------------------------------
// GEMM: partial[kc][row][col] = sum_{k in chunk} x[row][k] * W[col][k]
// Grid (16 col-tiles of 96, 16 K-chunks) = 256 blocks = 1 per CU.
// Micro-tile 8 rows x 3 cols (cols strided 32: conflict-free LDS reads).
// Double-buffered LDS, register prefetch, one barrier per stage.
// Block (0,0) also zeroes the NMS record counters for this replay.
// ---------------------------------------------------------------------------
__global__ __launch_bounds__(256) void gemm_splitk(
    const float* __restrict__ x, const float* __restrict__ W,
    float* __restrict__ partial, int* __restrict__ cnts)
{
    __shared__ float sx[2][16 * XS];
    __shared__ float sw[2][16 * WSD];

    const int t   = threadIdx.x;
    if (blockIdx.x == 0 && blockIdx.y == 0 && t == 0) { cnts[0] = 0; cnts[1] = 0; }

    const int c0  = blockIdx.x * 96;
    const int k0  = blockIdx.y * KCHUNK;
    const int r8  = (t >> 5) << 3;   // 8-row group: 0,8,...,56
    const int cgi = t & 31;          // cols cgi + {0,32,64}
    const int kk0 = t & 15;
    const int g0  = t >> 4;          // 0..15

    float acc[8][3];
#pragma unroll
    for (int i = 0; i < 8; ++i)
#pragma unroll
        for (int j = 0; j < 3; ++j) acc[i][j] = 0.f;

    const float* wp[6];
#pragma unroll
    for (int p = 0; p < 6; ++p) {
        int gc = c0 + p * 16 + g0;
        if (gc >= NCOL) gc = NCOL - 1;       // clamp; garbage cols ignored downstream
        wp[p] = W + (size_t)gc * KDIM + kk0;
    }

    float xr[4], wr[6];
    {   // prologue: stage 0 -> regs -> buf0
        const int kb = k0;
#pragma unroll
        for (int p = 0; p < 4; ++p) xr[p] = x[(p * 16 + g0) * KDIM + kb + kk0];
#pragma unroll
        for (int p = 0; p < 6; ++p) wr[p] = wp[p][kb];
#pragma unroll
        for (int p = 0; p < 4; ++p) sx[0][kk0 * XS + p * 16 + g0] = xr[p];
#pragma unroll
        for (int p = 0; p < 6; ++p) sw[0][kk0 * WSD + p * 16 + g0] = wr[p];
    }

    for (int s = 0; s < NSTAGE; ++s) {
        const int cb = s & 1;
        if (s + 1 < NSTAGE) {            // issue next-stage global loads now
            const int kb = k0 + ((s + 1) << 4);
#pragma unroll
            for (int p = 0; p < 4; ++p) xr[p] = x[(p * 16 + g0) * KDIM + kb + kk0];
#pragma unroll
            for (int p = 0; p < 6; ++p) wr[p] = wp[p][kb];
        }
        __syncthreads();                 // buf[cb] writes (prev iter) visible
        const float* cx = sx[cb];
        const float* cw = sw[cb];
#pragma unroll
        for (int kk = 0; kk < 16; ++kk) {
            const float4 a0 = *(const float4*)&cx[kk * XS + r8];
            const float4 a1 = *(const float4*)&cx[kk * XS + r8 + 4];
            const float w0 = cw[kk * WSD + cgi];
            const float w1 = cw[kk * WSD + cgi + 32];
            const float w2 = cw[kk * WSD + cgi + 64];
            const float av[8] = {a0.x, a0.y, a0.z, a0.w, a1.x, a1.y, a1.z, a1.w};
#pragma unroll
            for (int i = 0; i < 8; ++i) {
                acc[i][0] = fmaf(av[i], w0, acc[i][0]);
                acc[i][1] = fmaf(av[i], w1, acc[i][1]);
                acc[i][2] = fmaf(av[i], w2, acc[i][2]);
            }
        }
        if (s + 1 < NSTAGE) {            // store prefetched regs -> other buffer
#pragma unroll
            for (int p = 0; p < 4; ++p) sx[cb ^ 1][kk0 * XS + p * 16 + g0] = xr[p];
#pragma unroll
            for (int p = 0; p < 6; ++p) sw[cb ^ 1][kk0 * WSD + p * 16 + g0] = wr[p];
        }
    }

    float* pb = partial + (size_t)blockIdx.y * (B_ * CPAD) + c0 + cgi;
#pragma unroll
    for (int i = 0; i < 8; ++i)
#pragma unroll
        for (int p = 0; p < 3; ++p)
            pb[(size_t)(r8 + i) * CPAD + 32 * p] = acc[i][p];
}

// ---------------------------------------------------------------------------
// Fused: split-K combine + bias + decode + UNMASKED pack into out.
// 8 cells per 256-thr block. Also appends per-valid compact NMS records
// (idx, score, box) to global lists via device-scope atomics.
// out layout: out[slot*NCELL + n][25] = [boxes*448, score, labels(20)]
// ---------------------------------------------------------------------------
__global__ __launch_bounds__(256) void combine_prep_pack(
    const float* __restrict__ partial, const float* __restrict__ bias,
    float* __restrict__ out, int* __restrict__ cnts,
    int* __restrict__ recIdx, float* __restrict__ recSc,
    float4* __restrict__ recBox)
{
    __shared__ float sa[8][30];
    const int t    = threadIdx.x;
    const int base = blockIdx.x * 8;             // 392 * 8 == 3136 exactly

    if (t < 240) {
        const int n   = base + t / 30;
        const int col = t % 30;
        const int row = n / 49;                  // 1470/30 = 49 cells per batch-row
        const int cr  = (n % 49) * 30 + col;
        float s = 0.f;
#pragma unroll
        for (int k = 0; k < SPLITK; ++k)
            s += partial[(size_t)k * (B_ * CPAD) + (size_t)row * CPAD + cr];
        s += bias[cr];
        sa[t / 30][col] = s;
        if (col >= 10) {                          // labels -> both slots (unmasked)
            out[(size_t)n * 25 + 5 + (col - 10)] = s;
            out[(size_t)(NCELL + n) * 25 + 5 + (col - 10)] = s;
        }
    }
    __syncthreads();

    if (t < 8) {
        const int n = base + t;
        const float* a = sa[t];
        float mv = a[10]; int mi = 0;
#pragma unroll
        for (int j = 1; j < 20; ++j) {
            float v = a[10 + j];
            if (v > mv) { mv = v; mi = j; }      // strict > => first-index tie-break
        }
        const float lp = (float)mi;
        const int gx = n % 7, gy = (n / 7) % 7;
        const float cw = 1.0f / 7.0f;
        const float nx = (float)gx * cw, ny = (float)gy * cw;
#pragma unroll
        for (int sl = 0; sl < 2; ++sl) {
            const int off = 5 * sl;
            const float bx0 = a[off], bx1 = a[off + 1];
            const float w_ = a[off + 2], h_ = a[off + 3];
            const float sc = a[off + 5];         // faithful port quirk: off+5
            const float cx = bx0 * cw + nx, cy = bx1 * cw + ny;
            const float X1 = cx - 0.5f * w_, Y1 = cy - 0.5f * h_;
            const float X2 = cx + 0.5f * w_, Y2 = cy + 0.5f * h_;
            const float b0 = X1 - 0.5f * X2;
            const float b1 = Y1 - 0.5f * Y2;
            const float b2 = X1 + 0.5f * X2;
            const float b3 = Y1 + 0.5f * Y2;
            float* orow = out + (size_t)(sl * NCELL + n) * 25;
            orow[0] = b0 * 448.0f;
            orow[1] = b1 * 448.0f;
            orow[2] = b2 * 448.0f;
            orow[3] = b3 * 448.0f;
            orow[4] = sc;
            if (sc * lp > 0.5f) {                 // valid -> append record
                int p = atomicAdd(&cnts[sl], 1);
                recIdx[sl * NCELL + p] = n;
                recSc [sl * NCELL + p] = sc;
                recBox[sl * NCELL + p] = make_float4(b0, b1, b2, b3);
            }
        }
    }
}

// ---------------------------------------------------------------------------
// Inverted greedy NMS on compacted records + row masking of out.
// One 256-thread block per slot. Records -> LDS SoA (coalesced); alive set
// as per-thread register bitmask; 2 barriers per pick. Afterwards zero all
// non-kept out rows (store-only).
// Order of records is schedule-dependent, but reduction is by
// (score, min original index) and filtering is order-independent ->
// deterministic, reference-identical result.
// ---------------------------------------------------------------------------
__global__ __launch_bounds__(NMS_T) void nms_mask(
    const int* __restrict__ cnts, const int* __restrict__ recIdx,
    const float* __restrict__ recSc, const float4* __restrict__ recBox,
    float* __restrict__ out)
{
    __shared__ float sX1[NCELL], sY1[NCELL], sX2[NCELL], sY2[NCELL];
    __shared__ float sSc[NCELL];
    __shared__ int   sIdx[NCELL];
    __shared__ unsigned char kp[NCELL];
    __shared__ float rv[4];
    __shared__ int   rn[4], rj[4];
    __shared__ int   pickJ, pickN;

    const int slot = blockIdx.x;
    const int t = threadIdx.x;
    const int cnt = cnts[slot];
    const int rb = slot * NCELL;

    unsigned am = 0;                     // alive bitmask for my <=13 entries
#pragma unroll
    for (int q = 0; q < QMAX; ++q) {
        const int j = t + q * NMS_T;
        if (j < cnt) {
            const float4 bb = recBox[rb + j];
            sX1[j] = bb.x; sY1[j] = bb.y; sX2[j] = bb.z; sY2[j] = bb.w;
            sSc[j] = recSc[rb + j];
            sIdx[j] = recIdx[rb + j];
            am |= 1u << q;
        }
    }
    for (int n = t; n < NCELL; n += NMS_T) kp[n] = 0;
    __syncthreads();

    for (;;) {
        // ---- argmax over alive: (score desc, original index asc) ----
        float bv = -1e30f; int bn = 0x7fffffff; int bj = -1;
#pragma unroll
        for (int q = 0; q < QMAX; ++q)
            if ((am >> q) & 1u) {
                const int j = t + q * NMS_T;
                const float v = sSc[j];
                const int   n = sIdx[j];
                if (v > bv || (v == bv && n < bn)) { bv = v; bn = n; bj = j; }
            }
#pragma unroll
        for (int o = 32; o > 0; o >>= 1) {
            const float ov = __shfl_down(bv, o);
            const int   on = __shfl_down(bn, o);
            const int   oj = __shfl_down(bj, o);
            if (ov > bv || (ov == bv && on < bn)) { bv = ov; bn = on; bj = oj; }
        }
        if ((t & 63) == 0) { rv[t >> 6] = bv; rn[t >> 6] = bn; rj[t >> 6] = bj; }
        __syncthreads();
        if (t == 0) {
            float v2 = rv[0]; int n2 = rn[0]; int j2 = rj[0];
#pragma unroll
            for (int q = 1; q < 4; ++q)
                if (rv[q] > v2 || (rv[q] == v2 && rn[q] < n2)) { v2 = rv[q]; n2 = rn[q]; j2 = rj[q]; }
            if (v2 == -1e30f) { pickJ = -1; }
            else { pickJ = j2; pickN = n2; kp[n2] = 1; }
        }
        __syncthreads();
        const int pj = pickJ;
        if (pj < 0) break;
        const int pn = pickN;
        const float px1 = sX1[pj], py1 = sY1[pj], px2 = sX2[pj], py2 = sY2[pj];
        const float pa = (px2 - px1) * (py2 - py1);

        // ---- retain only entries with IoU >= 0.5 vs pick (and not pick) ----
#pragma unroll
        for (int q = 0; q < QMAX; ++q)
            if ((am >> q) & 1u) {
                const int j = t + q * NMS_T;
                const float x1 = sX1[j], y1 = sY1[j], x2 = sX2[j], y2 = sY2[j];
                const float an = (x2 - x1) * (y2 - y1);
                const float ix1 = fmaxf(x1, px1), iy1 = fmaxf(y1, py1);
                const float ix2 = fminf(x2, px2), iy2 = fminf(y2, py2);
                const float inter = fmaxf(ix2 - ix1, 0.f) * fmaxf(iy2 - iy1, 0.f);
                const float iou = inter / (pa + an - inter);   // IEEE divide
                if (!(iou >= 0.5f) || sIdx[j] == pn) am &= ~(1u << q);
            }
        // (next iteration's barriers order rv/pick reuse)
    }

    __syncthreads();
    // ---- mask: zero every non-kept row of this slot (store-only) ----
    for (int n = t; n < NCELL; n += NMS_T) {
        if (!kp[n]) {
            float* orow = out + (size_t)(rb + n) * 25;
#pragma unroll
            for (int c = 0; c < 25; ++c) orow[c] = 0.f;
        }
    }
}

// ---------------------------------------------------------------------------
extern "C" void kernel_launch(void* const* d_in, const int* in_sizes, int n_in,
                              void* d_out, int out_size, void* d_ws, size_t ws_size,
                              hipStream_t stream)
{
    const float* x = (const float*)d_in[0];
    const float* W = (const float*)d_in[1];
    const float* b = (const float*)d_in[2];
    float* out = (float*)d_out;

    float*  ws      = (float*)d_ws;
    float*  partial = ws;                                       // 16*64*1536 f (16B-aligned)
    float4* recBox  = (float4*)(partial + (size_t)SPLITK * B_ * CPAD);  // 2*3136 float4
    float*  recSc   = (float*)(recBox + 2 * NCELL);             // 2*3136 f
    int*    recIdx  = (int*)(recSc + 2 * NCELL);                // 2*3136 i
    int*    cnts    = recIdx + 2 * NCELL;                       // 2 i

    hipLaunchKernelGGL(gemm_splitk, dim3(16, SPLITK), dim3(256), 0, stream,
                       x, W, partial, cnts);
    hipLaunchKernelGGL(combine_prep_pack, dim3(NCELL / 8), dim3(256), 0, stream,
                       partial, b, out, cnts, recIdx, recSc, recBox);
    hipLaunchKernelGGL(nms_mask, dim3(2), dim3(NMS_T), 0, stream,
                       cnts, recIdx, recSc, recBox, out);
}

// Round 7
// 44.033 us; speedup vs baseline: 1.5925x; 1.1394x over previous
//
#include <hip/hip_runtime.h>

#define B_     64
#define KDIM   2304
#define NCOL   1470
#define NCELL  3136   // 64 * 7 * 7
#define CPAD   1536
#define SPLITK 16
#define KCHUNK 144    // KDIM / SPLITK
#define NSTAGE 9      // KCHUNK / 16
#define XS     68     // sx row stride (writes 2-way free, reads broadcast)
#define WSD    100    // sw col stride (writes 2-way free, reads conflict-free)
#define NMS_T  256
#define QMAX   13     // ceil(NCELL / NMS_T)

// ---------------------------------------------------------------------------
// GEMM: partial[kc][row][col] = sum_{k in chunk} x[row][k] * W[col][k]
// Grid (16 col-tiles of 96, 16 K-chunks) = 256 blocks = 1 per CU.
// Micro-tile 8 rows x 3 cols (cols strided 32: conflict-free LDS reads).
// Double-buffered LDS, register prefetch, one barrier per stage.
// Block (0,0) also zeroes the NMS record counters for this replay.
// ---------------------------------------------------------------------------
__global__ __launch_bounds__(256) void gemm_splitk(
    const float* __restrict__ x, const float* __restrict__ W,
    float* __restrict__ partial, int* __restrict__ cnts)
{
    __shared__ float sx[2][16 * XS];
    __shared__ float sw[2][16 * WSD];

    const int t = threadIdx.x;
    if (blockIdx.x == 0 && blockIdx.y == 0 && t == 0) { cnts[0] = 0; cnts[1] = 0; }

    const int c0  = blockIdx.x * 96;
    const int k0  = blockIdx.y * KCHUNK;
    const int r8  = (t >> 5) << 3;   // 8-row group: 0,8,...,56
    const int cgi = t & 31;          // cols cgi + {0,32,64}
    const int kk0 = t & 15;
    const int g0  = t >> 4;          // 0..15

    float acc[8][3];
#pragma unroll
    for (int i = 0; i < 8; ++i)
#pragma unroll
        for (int j = 0; j < 3; ++j) acc[i][j] = 0.f;

    const float* wp[6];
#pragma unroll
    for (int p = 0; p < 6; ++p) {
        int gc = c0 + p * 16 + g0;
        if (gc >= NCOL) gc = NCOL - 1;       // clamp; garbage cols ignored downstream
        wp[p] = W + (size_t)gc * KDIM + kk0;
    }

    float xr[4], wr[6];
    {   // prologue: stage 0 -> regs -> buf0
        const int kb = k0;
#pragma unroll
        for (int p = 0; p < 4; ++p) xr[p] = x[(p * 16 + g0) * KDIM + kb + kk0];
#pragma unroll
        for (int p = 0; p < 6; ++p) wr[p] = wp[p][kb];
#pragma unroll
        for (int p = 0; p < 4; ++p) sx[0][kk0 * XS + p * 16 + g0] = xr[p];
#pragma unroll
        for (int p = 0; p < 6; ++p) sw[0][kk0 * WSD + p * 16 + g0] = wr[p];
    }

    for (int s = 0; s < NSTAGE; ++s) {
        const int cb = s & 1;
        if (s + 1 < NSTAGE) {            // issue next-stage global loads now
            const int kb = k0 + ((s + 1) << 4);
#pragma unroll
            for (int p = 0; p < 4; ++p) xr[p] = x[(p * 16 + g0) * KDIM + kb + kk0];
#pragma unroll
            for (int p = 0; p < 6; ++p) wr[p] = wp[p][kb];
        }
        __syncthreads();                 // buf[cb] writes (prev iter) visible
        const float* cx = sx[cb];
        const float* cw = sw[cb];
#pragma unroll
        for (int kk = 0; kk < 16; ++kk) {
            const float4 a0 = *(const float4*)&cx[kk * XS + r8];
            const float4 a1 = *(const float4*)&cx[kk * XS + r8 + 4];
            const float w0 = cw[kk * WSD + cgi];
            const float w1 = cw[kk * WSD + cgi + 32];
            const float w2 = cw[kk * WSD + cgi + 64];
            const float av[8] = {a0.x, a0.y, a0.z, a0.w, a1.x, a1.y, a1.z, a1.w};
#pragma unroll
            for (int i = 0; i < 8; ++i) {
                acc[i][0] = fmaf(av[i], w0, acc[i][0]);
                acc[i][1] = fmaf(av[i], w1, acc[i][1]);
                acc[i][2] = fmaf(av[i], w2, acc[i][2]);
            }
        }
        if (s + 1 < NSTAGE) {            // store prefetched regs -> other buffer
#pragma unroll
            for (int p = 0; p < 4; ++p) sx[cb ^ 1][kk0 * XS + p * 16 + g0] = xr[p];
#pragma unroll
            for (int p = 0; p < 6; ++p) sw[cb ^ 1][kk0 * WSD + p * 16 + g0] = wr[p];
        }
    }

    float* pb = partial + (size_t)blockIdx.y * (B_ * CPAD) + c0 + cgi;
#pragma unroll
    for (int i = 0; i < 8; ++i)
#pragma unroll
        for (int p = 0; p < 3; ++p)
            pb[(size_t)(r8 + i) * CPAD + 32 * p] = acc[i][p];
}

// ---------------------------------------------------------------------------
// Fused: split-K combine + bias + decode + pack.
// Since keep ⊆ valid, rows that are INVALID here are known-zero in the final
// output -> write zeros now (wide). Valid rows get unmasked values + a
// compact NMS record (idx, score, box) + kp[m]=0 init.
// out layout: out[slot*NCELL + n][25] = [boxes*448, score, labels(20)]
// ---------------------------------------------------------------------------
__global__ __launch_bounds__(256) void combine_prep_pack(
    const float* __restrict__ partial, const float* __restrict__ bias,
    float* __restrict__ out, int* __restrict__ cnts,
    int* __restrict__ recIdx, float* __restrict__ recSc,
    float4* __restrict__ recBox, unsigned char* __restrict__ kp)
{
    __shared__ float sa[8][30];
    const int t    = threadIdx.x;
    const int base = blockIdx.x * 8;             // 392 * 8 == 3136 exactly

    if (t < 240) {
        const int n   = base + t / 30;
        const int col = t % 30;
        const int row = n / 49;                  // 1470/30 = 49 cells per batch-row
        const int cr  = (n % 49) * 30 + col;
        float s = 0.f;
#pragma unroll
        for (int k = 0; k < SPLITK; ++k)
            s += partial[(size_t)k * (B_ * CPAD) + (size_t)row * CPAD + cr];
        s += bias[cr];
        sa[t / 30][col] = s;
        if (col >= 10) {                          // labels -> both slots (unmasked)
            out[(size_t)n * 25 + 5 + (col - 10)] = s;
            out[(size_t)(NCELL + n) * 25 + 5 + (col - 10)] = s;
        }
    }
    __syncthreads();

    if (t < 8) {
        const int n = base + t;
        const float* a = sa[t];
        float mv = a[10]; int mi = 0;
#pragma unroll
        for (int j = 1; j < 20; ++j) {
            float v = a[10 + j];
            if (v > mv) { mv = v; mi = j; }      // strict > => first-index tie-break
        }
        const float lp = (float)mi;
        const int gx = n % 7, gy = (n / 7) % 7;
        const float cw = 1.0f / 7.0f;
        const float nx = (float)gx * cw, ny = (float)gy * cw;
#pragma unroll
        for (int sl = 0; sl < 2; ++sl) {
            const int off = 5 * sl;
            const float bx0 = a[off], bx1 = a[off + 1];
            const float w_ = a[off + 2], h_ = a[off + 3];
            const float sc = a[off + 5];         // faithful port quirk: off+5
            const float cx = bx0 * cw + nx, cy = bx1 * cw + ny;
            const float X1 = cx - 0.5f * w_, Y1 = cy - 0.5f * h_;
            const float X2 = cx + 0.5f * w_, Y2 = cy + 0.5f * h_;
            const float b0 = X1 - 0.5f * X2;
            const float b1 = Y1 - 0.5f * Y2;
            const float b2 = X1 + 0.5f * X2;
            const float b3 = Y1 + 0.5f * Y2;
            const int   m = sl * NCELL + n;
            float* orow = out + (size_t)m * 25;
            if (sc * lp > 0.5f) {                // valid: unmasked row + record
                orow[0] = b0 * 448.0f;
                orow[1] = b1 * 448.0f;
                orow[2] = b2 * 448.0f;
                orow[3] = b3 * 448.0f;
                orow[4] = sc;
                kp[m] = 0;
                int p = atomicAdd(&cnts[sl], 1);
                recIdx[sl * NCELL + p] = n;
                recSc [sl * NCELL + p] = sc;
                recBox[sl * NCELL + p] = make_float4(b0, b1, b2, b3);
            } else {                             // invalid: keep ⊆ valid -> zero row
#pragma unroll
                for (int c = 0; c < 25; ++c) orow[c] = 0.f;
            }
        }
    }
}

// ---------------------------------------------------------------------------
// Inverted greedy NMS on compacted records. One 256-thr block per slot.
// Records -> LDS SoA (coalesced); alive set = per-thread register bitmask;
// 2 barriers per pick. Writes ONLY kp[pick]=1 (no bulk out traffic).
// Record order is schedule-dependent, but reduction is by (score desc,
// original index asc) and filtering is order-independent -> deterministic.
// ---------------------------------------------------------------------------
__global__ __launch_bounds__(NMS_T) void nms_rec(
    const int* __restrict__ cnts, const int* __restrict__ recIdx,
    const float* __restrict__ recSc, const float4* __restrict__ recBox,
    unsigned char* __restrict__ kp)
{
    __shared__ float sX1[NCELL], sY1[NCELL], sX2[NCELL], sY2[NCELL];
    __shared__ float sSc[NCELL];
    __shared__ int   sIdx[NCELL];
    __shared__ float rv[4];
    __shared__ int   rn[4], rj[4];
    __shared__ int   pickJ, pickN;

    const int slot = blockIdx.x;
    const int t = threadIdx.x;
    const int cnt = cnts[slot];
    const int rb = slot * NCELL;

    unsigned am = 0;                     // alive bitmask for my <=13 entries
#pragma unroll
    for (int q = 0; q < QMAX; ++q) {
        const int j = t + q * NMS_T;
        if (j < cnt) {
            const float4 bb = recBox[rb + j];
            sX1[j] = bb.x; sY1[j] = bb.y; sX2[j] = bb.z; sY2[j] = bb.w;
            sSc[j] = recSc[rb + j];
            sIdx[j] = recIdx[rb + j];
            am |= 1u << q;
        }
    }
    __syncthreads();

    for (;;) {
        // ---- argmax over alive: (score desc, original index asc) ----
        float bv = -1e30f; int bn = 0x7fffffff; int bj = -1;
#pragma unroll
        for (int q = 0; q < QMAX; ++q)
            if ((am >> q) & 1u) {
                const int j = t + q * NMS_T;
                const float v = sSc[j];
                const int   n = sIdx[j];
                if (v > bv || (v == bv && n < bn)) { bv = v; bn = n; bj = j; }
            }
#pragma unroll
        for (int o = 32; o > 0; o >>= 1) {
            const float ov = __shfl_down(bv, o);
            const int   on = __shfl_down(bn, o);
            const int   oj = __shfl_down(bj, o);
            if (ov > bv || (ov == bv && on < bn)) { bv = ov; bn = on; bj = oj; }
        }
        if ((t & 63) == 0) { rv[t >> 6] = bv; rn[t >> 6] = bn; rj[t >> 6] = bj; }
        __syncthreads();
        if (t == 0) {
            float v2 = rv[0]; int n2 = rn[0]; int j2 = rj[0];
#pragma unroll
            for (int q = 1; q < 4; ++q)
                if (rv[q] > v2 || (rv[q] == v2 && rn[q] < n2)) { v2 = rv[q]; n2 = rn[q]; j2 = rj[q]; }
            if (v2 == -1e30f) { pickJ = -1; }
            else { pickJ = j2; pickN = n2; kp[rb + n2] = 1; }
        }
        __syncthreads();
        const int pj = pickJ;
        if (pj < 0) break;
        const int pn = pickN;
        const float px1 = sX1[pj], py1 = sY1[pj], px2 = sX2[pj], py2 = sY2[pj];
        const float pa = (px2 - px1) * (py2 - py1);

        // ---- retain only entries with IoU >= 0.5 vs pick (and not pick) ----
#pragma unroll
        for (int q = 0; q < QMAX; ++q)
            if ((am >> q) & 1u) {
                const int j = t + q * NMS_T;
                const float x1 = sX1[j], y1 = sY1[j], x2 = sX2[j], y2 = sY2[j];
                const float an = (x2 - x1) * (y2 - y1);
                const float ix1 = fmaxf(x1, px1), iy1 = fmaxf(y1, py1);
                const float ix2 = fminf(x2, px2), iy2 = fminf(y2, py2);
                const float inter = fmaxf(ix2 - ix1, 0.f) * fmaxf(iy2 - iy1, 0.f);
                const float iou = inter / (pa + an - inter);   // IEEE divide
                if (!(iou >= 0.5f) || sIdx[j] == pn) am &= ~(1u << q);
            }
        // next iteration's barriers order rv/pick reuse
    }
}

// ---------------------------------------------------------------------------
// Zero the valid-but-not-kept rows. Wide (64 blocks); work = record count.
// ---------------------------------------------------------------------------
__global__ __launch_bounds__(256) void mask_rows(
    const int* __restrict__ cnts, const int* __restrict__ recIdx,
    const unsigned char* __restrict__ kp, float* __restrict__ out)
{
    const int tid = blockIdx.x * 256 + threadIdx.x;
    const int nthr = 64 * 256;
#pragma unroll
    for (int sl = 0; sl < 2; ++sl) {
        const int cnt = cnts[sl];
        for (int j = tid; j < cnt; j += nthr) {
            const int n = recIdx[sl * NCELL + j];
            const int m = sl * NCELL + n;
            if (!kp[m]) {
                float* orow = out + (size_t)m * 25;
#pragma unroll
                for (int c = 0; c < 25; ++c) orow[c] = 0.f;
            }
        }
    }
}

// ---------------------------------------------------------------------------
extern "C" void kernel_launch(void* const* d_in, const int* in_sizes, int n_in,
                              void* d_out, int out_size, void* d_ws, size_t ws_size,
                              hipStream_t stream)
{
    const float* x = (const float*)d_in[0];
    const float* W = (const float*)d_in[1];
    const float* b = (const float*)d_in[2];
    float* out = (float*)d_out;

    float*  ws      = (float*)d_ws;
    float*  partial = ws;                                       // 16*64*1536 f
    float4* recBox  = (float4*)(partial + (size_t)SPLITK * B_ * CPAD);  // 2*3136 f4
    float*  recSc   = (float*)(recBox + 2 * NCELL);             // 2*3136 f
    int*    recIdx  = (int*)(recSc + 2 * NCELL);                // 2*3136 i
    int*    cnts    = recIdx + 2 * NCELL;                       // 2 i
    unsigned char* kp = (unsigned char*)(cnts + 2);             // 2*3136 B

    hipLaunchKernelGGL(gemm_splitk, dim3(16, SPLITK), dim3(256), 0, stream,
                       x, W, partial, cnts);
    hipLaunchKernelGGL(combine_prep_pack, dim3(NCELL / 8), dim3(256), 0, stream,
                       partial, b, out, cnts, recIdx, recSc, recBox, kp);
    hipLaunchKernelGGL(nms_rec, dim3(2), dim3(NMS_T), 0, stream,
                       cnts, recIdx, recSc, recBox, kp);
    hipLaunchKernelGGL(mask_rows, dim3(64), dim3(256), 0, stream,
                       cnts, recIdx, kp, out);
}

// Round 8
// 33.045 us; speedup vs baseline: 2.1220x; 1.3325x over previous
//
#include <hip/hip_runtime.h>

#define B_     64
#define KDIM   2304
#define NCOL   1470
#define NCELL  3136   // 64 * 7 * 7
#define CPAD   1536
#define SPLITK 16
#define KCHUNK 144    // KDIM / SPLITK
#define NSTAGE 9      // KCHUNK / 16
#define XS     68     // sx row stride (writes 2-way free, reads broadcast)
#define WSD    100    // sw col stride (writes 2-way free, reads conflict-free)
#define NMS_T  1024
#define QMAX   4      // ceil(NCELL / NMS_T)

// ---------------------------------------------------------------------------
// GEMM: partial[kc][row][col] = sum_{k in chunk} x[row][k] * W[col][k]
// Grid (16 col-tiles of 96, 16 K-chunks) = 256 blocks = 1 per CU.
// Micro-tile 8 rows x 3 cols (cols strided 32: conflict-free LDS reads).
// Double-buffered LDS, register prefetch, one barrier per stage.
// ---------------------------------------------------------------------------
__global__ __launch_bounds__(256) void gemm_splitk(
    const float* __restrict__ x, const float* __restrict__ W,
    float* __restrict__ partial)
{
    __shared__ float sx[2][16 * XS];
    __shared__ float sw[2][16 * WSD];

    const int t   = threadIdx.x;
    const int c0  = blockIdx.x * 96;
    const int k0  = blockIdx.y * KCHUNK;
    const int r8  = (t >> 5) << 3;   // 8-row group: 0,8,...,56
    const int cgi = t & 31;          // cols cgi + {0,32,64}
    const int kk0 = t & 15;
    const int g0  = t >> 4;          // 0..15

    float acc[8][3];
#pragma unroll
    for (int i = 0; i < 8; ++i)
#pragma unroll
        for (int j = 0; j < 3; ++j) acc[i][j] = 0.f;

    const float* wp[6];
#pragma unroll
    for (int p = 0; p < 6; ++p) {
        int gc = c0 + p * 16 + g0;
        if (gc >= NCOL) gc = NCOL - 1;       // clamp; garbage cols ignored downstream
        wp[p] = W + (size_t)gc * KDIM + kk0;
    }

    float xr[4], wr[6];
    {   // prologue: stage 0 -> regs -> buf0
        const int kb = k0;
#pragma unroll
        for (int p = 0; p < 4; ++p) xr[p] = x[(p * 16 + g0) * KDIM + kb + kk0];
#pragma unroll
        for (int p = 0; p < 6; ++p) wr[p] = wp[p][kb];
#pragma unroll
        for (int p = 0; p < 4; ++p) sx[0][kk0 * XS + p * 16 + g0] = xr[p];
#pragma unroll
        for (int p = 0; p < 6; ++p) sw[0][kk0 * WSD + p * 16 + g0] = wr[p];
    }

    for (int s = 0; s < NSTAGE; ++s) {
        const int cb = s & 1;
        if (s + 1 < NSTAGE) {            // issue next-stage global loads now
            const int kb = k0 + ((s + 1) << 4);
#pragma unroll
            for (int p = 0; p < 4; ++p) xr[p] = x[(p * 16 + g0) * KDIM + kb + kk0];
#pragma unroll
            for (int p = 0; p < 6; ++p) wr[p] = wp[p][kb];
        }
        __syncthreads();                 // buf[cb] writes (prev iter) visible
        const float* cx = sx[cb];
        const float* cw = sw[cb];
#pragma unroll
        for (int kk = 0; kk < 16; ++kk) {
            const float4 a0 = *(const float4*)&cx[kk * XS + r8];
            const float4 a1 = *(const float4*)&cx[kk * XS + r8 + 4];
            const float w0 = cw[kk * WSD + cgi];
            const float w1 = cw[kk * WSD + cgi + 32];
            const float w2 = cw[kk * WSD + cgi + 64];
            const float av[8] = {a0.x, a0.y, a0.z, a0.w, a1.x, a1.y, a1.z, a1.w};
#pragma unroll
            for (int i = 0; i < 8; ++i) {
                acc[i][0] = fmaf(av[i], w0, acc[i][0]);
                acc[i][1] = fmaf(av[i], w1, acc[i][1]);
                acc[i][2] = fmaf(av[i], w2, acc[i][2]);
            }
        }
        if (s + 1 < NSTAGE) {            // store prefetched regs -> other buffer
#pragma unroll
            for (int p = 0; p < 4; ++p) sx[cb ^ 1][kk0 * XS + p * 16 + g0] = xr[p];
#pragma unroll
            for (int p = 0; p < 6; ++p) sw[cb ^ 1][kk0 * WSD + p * 16 + g0] = wr[p];
        }
    }

    float* pb = partial + (size_t)blockIdx.y * (B_ * CPAD) + c0 + cgi;
#pragma unroll
    for (int i = 0; i < 8; ++i)
#pragma unroll
        for (int p = 0; p < 3; ++p)
            pb[(size_t)(r8 + i) * CPAD + 32 * p] = acc[i][p];
}

// ---------------------------------------------------------------------------
// Fused split-K combine + bias + per-cell decode (8 cells per 256-thr block).
// Dense outputs, NO atomics: labels[n*20], boxes[m*4], scores[m], valid[m].
// ---------------------------------------------------------------------------
__global__ __launch_bounds__(256) void combine_prep(
    const float* __restrict__ partial, const float* __restrict__ bias,
    float* __restrict__ labels, float* __restrict__ boxes,
    float* __restrict__ scores, int* __restrict__ valid)
{
    __shared__ float sa[8][30];
    const int t    = threadIdx.x;
    const int base = blockIdx.x * 8;             // 392 * 8 == 3136 exactly

    if (t < 240) {
        const int n   = base + t / 30;
        const int col = t % 30;
        const int row = n / 49;                  // 1470/30 = 49 cells per batch-row
        const int cr  = (n % 49) * 30 + col;
        float s = 0.f;
#pragma unroll
        for (int k = 0; k < SPLITK; ++k)
            s += partial[(size_t)k * (B_ * CPAD) + (size_t)row * CPAD + cr];
        s += bias[cr];
        sa[t / 30][col] = s;
        if (col >= 10) labels[(size_t)n * 20 + (col - 10)] = s;
    }
    __syncthreads();

    if (t < 8) {
        const int n = base + t;
        const float* a = sa[t];
        float mv = a[10]; int mi = 0;
#pragma unroll
        for (int j = 1; j < 20; ++j) {
            float v = a[10 + j];
            if (v > mv) { mv = v; mi = j; }      // strict > => first-index tie-break
        }
        const float lp = (float)mi;
        const int gx = n % 7, gy = (n / 7) % 7;
        const float cw = 1.0f / 7.0f;
        const float nx = (float)gx * cw, ny = (float)gy * cw;
#pragma unroll
        for (int sl = 0; sl < 2; ++sl) {
            const int off = 5 * sl;
            const float bx0 = a[off], bx1 = a[off + 1];
            const float w_ = a[off + 2], h_ = a[off + 3];
            const float sc = a[off + 5];         // faithful port quirk: off+5
            const float cx = bx0 * cw + nx, cy = bx1 * cw + ny;
            const float X1 = cx - 0.5f * w_, Y1 = cy - 0.5f * h_;
            const float X2 = cx + 0.5f * w_, Y2 = cy + 0.5f * h_;
            const int m = sl * NCELL + n;
            boxes[m * 4 + 0] = X1 - 0.5f * X2;
            boxes[m * 4 + 1] = Y1 - 0.5f * Y2;
            boxes[m * 4 + 2] = X1 + 0.5f * X2;
            boxes[m * 4 + 3] = Y1 + 0.5f * Y2;
            scores[m] = sc;
            valid[m] = (sc * lp > 0.5f) ? 1 : 0;
        }
    }
}

// ---------------------------------------------------------------------------
// Inverted greedy NMS, register-bitmask over dense arrays. One 1024-thread
// block per slot. Stage all entries coalesced into LDS SoA (~66 KB); alive
// set = 4 bits/thread in a register; 2 barriers per pick; no LDS/global
// atomics. Writes dense keep[] at the end.
// ---------------------------------------------------------------------------
__global__ __launch_bounds__(NMS_T) void nms_kernel(
    const float* __restrict__ boxes, const float* __restrict__ scores,
    const int* __restrict__ valid, float* __restrict__ keep)
{
    __shared__ float sX1[NCELL], sY1[NCELL], sX2[NCELL], sY2[NCELL];
    __shared__ float sSc[NCELL];
    __shared__ unsigned char kp[NCELL];
    __shared__ float rv[16];
    __shared__ int   rn[16];
    __shared__ int   pickN;

    const int slot = blockIdx.x;
    const int base = slot * NCELL;
    const int t = threadIdx.x;

    unsigned am = 0;                     // alive bitmask for my <=4 entries
#pragma unroll
    for (int q = 0; q < QMAX; ++q) {
        const int n = t + q * NMS_T;
        if (n < NCELL) {
            const float4 bb = *(const float4*)&boxes[(size_t)(base + n) * 4];
            sX1[n] = bb.x; sY1[n] = bb.y; sX2[n] = bb.z; sY2[n] = bb.w;
            sSc[n] = scores[base + n];
            kp[n] = 0;
            if (valid[base + n]) am |= 1u << q;
        }
    }
    __syncthreads();

    for (;;) {
        // ---- argmax over alive: (score desc, index asc) ----
        float bv = -1e30f; int bn = 0x7fffffff;
#pragma unroll
        for (int q = 0; q < QMAX; ++q)
            if ((am >> q) & 1u) {
                const int n = t + q * NMS_T;
                const float v = sSc[n];
                if (v > bv || (v == bv && n < bn)) { bv = v; bn = n; }
            }
#pragma unroll
        for (int o = 32; o > 0; o >>= 1) {
            const float ov = __shfl_down(bv, o);
            const int   on = __shfl_down(bn, o);
            if (ov > bv || (ov == bv && on < bn)) { bv = ov; bn = on; }
        }
        if ((t & 63) == 0) { rv[t >> 6] = bv; rn[t >> 6] = bn; }
        __syncthreads();
        if (t == 0) {
            float v2 = rv[0]; int n2 = rn[0];
#pragma unroll
            for (int q = 1; q < 16; ++q)
                if (rv[q] > v2 || (rv[q] == v2 && rn[q] < n2)) { v2 = rv[q]; n2 = rn[q]; }
            if (v2 == -1e30f) { pickN = -1; }
            else { pickN = n2; kp[n2] = 1; }
        }
        __syncthreads();
        const int pn = pickN;
        if (pn < 0) break;
        const float px1 = sX1[pn], py1 = sY1[pn], px2 = sX2[pn], py2 = sY2[pn];
        const float pa = (px2 - px1) * (py2 - py1);

        // ---- retain only entries with IoU >= 0.5 vs pick (and not pick) ----
#pragma unroll
        for (int q = 0; q < QMAX; ++q)
            if ((am >> q) & 1u) {
                const int n = t + q * NMS_T;
                const float x1 = sX1[n], y1 = sY1[n], x2 = sX2[n], y2 = sY2[n];
                const float an = (x2 - x1) * (y2 - y1);
                const float ix1 = fmaxf(x1, px1), iy1 = fmaxf(y1, py1);
                const float ix2 = fminf(x2, px2), iy2 = fminf(y2, py2);
                const float inter = fmaxf(ix2 - ix1, 0.f) * fmaxf(iy2 - iy1, 0.f);
                const float iou = inter / (pa + an - inter);   // IEEE divide
                if (!(iou >= 0.5f) || n == pn) am &= ~(1u << q);
            }
        // next iteration's barriers order rv/pick reuse
    }

    for (int n = t; n < NCELL; n += NMS_T)
        keep[base + n] = (float)kp[n];
}

// ---------------------------------------------------------------------------
// Pack output: (2, 3136, 25) = [boxes*448, score, labels(20)] * keep
// ---------------------------------------------------------------------------
__global__ void pack_out(const float* __restrict__ labels,
                         const float* __restrict__ boxes,
                         const float* __restrict__ scores,
                         const float* __restrict__ keep,
                         float* __restrict__ out)
{
    int idx = blockIdx.x * 256 + threadIdx.x;
    if (idx >= 2 * NCELL * 25) return;
    int c  = idx % 25;
    int sn = idx / 25;           // s*NCELL + n
    int n  = sn % NCELL;
    float k = keep[sn];
    float v;
    if (c < 4)       v = boxes[(size_t)sn * 4 + c] * 448.0f;
    else if (c == 4) v = scores[sn];
    else             v = labels[(size_t)n * 20 + (c - 5)];
    out[idx] = v * k;
}

// ---------------------------------------------------------------------------
extern "C" void kernel_launch(void* const* d_in, const int* in_sizes, int n_in,
                              void* d_out, int out_size, void* d_ws, size_t ws_size,
                              hipStream_t stream)
{
    const float* x = (const float*)d_in[0];
    const float* W = (const float*)d_in[1];
    const float* b = (const float*)d_in[2];
    float* out = (float*)d_out;

    float* ws      = (float*)d_ws;
    float* partial = ws;                                        // 16*64*1536
    float* labels  = partial + (size_t)SPLITK * B_ * CPAD;      // 3136*20
    float* boxes   = labels + (size_t)NCELL * 20;               // 3136*8
    float* scores  = boxes + (size_t)NCELL * 8;                 // 3136*2
    int*   valid   = (int*)(scores + (size_t)NCELL * 2);        // 3136*2
    float* keep    = (float*)(valid + (size_t)NCELL * 2);       // 3136*2

    hipLaunchKernelGGL(gemm_splitk, dim3(16, SPLITK), dim3(256), 0, stream,
                       x, W, partial);
    hipLaunchKernelGGL(combine_prep, dim3(NCELL / 8), dim3(256), 0, stream,
                       partial, b, labels, boxes, scores, valid);
    hipLaunchKernelGGL(nms_kernel, dim3(2), dim3(NMS_T), 0, stream,
                       boxes, scores, valid, keep);
    hipLaunchKernelGGL(pack_out, dim3((2 * NCELL * 25 + 255) / 256), dim3(256), 0, stream,
                       labels, boxes, scores, keep, out);
}

// Round 9
// 30.785 us; speedup vs baseline: 2.2777x; 1.0734x over previous
//
#include <hip/hip_runtime.h>

#define B_     64
#define KDIM   2304
#define NCOL   1470
#define NCELL  3136   // 64 * 7 * 7
#define CPAD   1536
#define SPLITK 16
#define KCHUNK 144    // KDIM / SPLITK
#define NSTAGE 9      // KCHUNK / 16
#define XS     68     // sx row stride (writes 2-way free, reads broadcast)
#define WSD    100    // sw col stride (writes 2-way free, reads conflict-free)
#define NMS_T  1024
#define QMAX   4      // ceil(NCELL / NMS_T)
#define OUTSZ  (2 * NCELL * 25)

// ---------------------------------------------------------------------------
// GEMM: partial[kc][row][col] = sum_{k in chunk} x[row][k] * W[col][k]
// Grid (16 col-tiles of 96, 16 K-chunks) = 256 blocks = 1 per CU.
// Micro-tile 8 rows x 3 cols (cols strided 32: conflict-free LDS reads).
// Double-buffered LDS, register prefetch, one barrier per stage.
// Also zero-fills `out` (final output is zero except NMS-picked rows,
// written later by nms_pick): 39200 float4 stores spread over 65536 threads,
// issued up front so they hide under the prologue's global-load latency.
// ---------------------------------------------------------------------------
__global__ __launch_bounds__(256) void gemm_splitk(
    const float* __restrict__ x, const float* __restrict__ W,
    float* __restrict__ partial, float* __restrict__ out)
{
    __shared__ float sx[2][16 * XS];
    __shared__ float sw[2][16 * WSD];

    const int t = threadIdx.x;

    {   // zero the output (one float4 per thread; first 39200 global threads)
        const int gt = (blockIdx.y * 16 + blockIdx.x) * 256 + t;
        if (gt < OUTSZ / 4)
            *(float4*)&out[gt * 4] = make_float4(0.f, 0.f, 0.f, 0.f);
    }

    const int c0  = blockIdx.x * 96;
    const int k0  = blockIdx.y * KCHUNK;
    const int r8  = (t >> 5) << 3;   // 8-row group: 0,8,...,56
    const int cgi = t & 31;          // cols cgi + {0,32,64}
    const int kk0 = t & 15;
    const int g0  = t >> 4;          // 0..15

    float acc[8][3];
#pragma unroll
    for (int i = 0; i < 8; ++i)
#pragma unroll
        for (int j = 0; j < 3; ++j) acc[i][j] = 0.f;

    const float* wp[6];
#pragma unroll
    for (int p = 0; p < 6; ++p) {
        int gc = c0 + p * 16 + g0;
        if (gc >= NCOL) gc = NCOL - 1;       // clamp; garbage cols ignored downstream
        wp[p] = W + (size_t)gc * KDIM + kk0;
    }

    float xr[4], wr[6];
    {   // prologue: stage 0 -> regs -> buf0
        const int kb = k0;
#pragma unroll
        for (int p = 0; p < 4; ++p) xr[p] = x[(p * 16 + g0) * KDIM + kb + kk0];
#pragma unroll
        for (int p = 0; p < 6; ++p) wr[p] = wp[p][kb];
#pragma unroll
        for (int p = 0; p < 4; ++p) sx[0][kk0 * XS + p * 16 + g0] = xr[p];
#pragma unroll
        for (int p = 0; p < 6; ++p) sw[0][kk0 * WSD + p * 16 + g0] = wr[p];
    }

    for (int s = 0; s < NSTAGE; ++s) {
        const int cb = s & 1;
        if (s + 1 < NSTAGE) {            // issue next-stage global loads now
            const int kb = k0 + ((s + 1) << 4);
#pragma unroll
            for (int p = 0; p < 4; ++p) xr[p] = x[(p * 16 + g0) * KDIM + kb + kk0];
#pragma unroll
            for (int p = 0; p < 6; ++p) wr[p] = wp[p][kb];
        }
        __syncthreads();                 // buf[cb] writes (prev iter) visible
        const float* cx = sx[cb];
        const float* cw = sw[cb];
#pragma unroll
        for (int kk = 0; kk < 16; ++kk) {
            const float4 a0 = *(const float4*)&cx[kk * XS + r8];
            const float4 a1 = *(const float4*)&cx[kk * XS + r8 + 4];
            const float w0 = cw[kk * WSD + cgi];
            const float w1 = cw[kk * WSD + cgi + 32];
            const float w2 = cw[kk * WSD + cgi + 64];
            const float av[8] = {a0.x, a0.y, a0.z, a0.w, a1.x, a1.y, a1.z, a1.w};
#pragma unroll
            for (int i = 0; i < 8; ++i) {
                acc[i][0] = fmaf(av[i], w0, acc[i][0]);
                acc[i][1] = fmaf(av[i], w1, acc[i][1]);
                acc[i][2] = fmaf(av[i], w2, acc[i][2]);
            }
        }
        if (s + 1 < NSTAGE) {            // store prefetched regs -> other buffer
#pragma unroll
            for (int p = 0; p < 4; ++p) sx[cb ^ 1][kk0 * XS + p * 16 + g0] = xr[p];
#pragma unroll
            for (int p = 0; p < 6; ++p) sw[cb ^ 1][kk0 * WSD + p * 16 + g0] = wr[p];
        }
    }

    float* pb = partial + (size_t)blockIdx.y * (B_ * CPAD) + c0 + cgi;
#pragma unroll
    for (int i = 0; i < 8; ++i)
#pragma unroll
        for (int p = 0; p < 3; ++p)
            pb[(size_t)(r8 + i) * CPAD + 32 * p] = acc[i][p];
}

// ---------------------------------------------------------------------------
// Fused split-K combine + bias + per-cell decode (8 cells per 256-thr block).
// Dense outputs, NO atomics: labels[n*20], boxes[m*4], scores[m], valid[m].
// ---------------------------------------------------------------------------
__global__ __launch_bounds__(256) void combine_prep(
    const float* __restrict__ partial, const float* __restrict__ bias,
    float* __restrict__ labels, float* __restrict__ boxes,
    float* __restrict__ scores, int* __restrict__ valid)
{
    __shared__ float sa[8][30];
    const int t    = threadIdx.x;
    const int base = blockIdx.x * 8;             // 392 * 8 == 3136 exactly

    if (t < 240) {
        const int n   = base + t / 30;
        const int col = t % 30;
        const int row = n / 49;                  // 1470/30 = 49 cells per batch-row
        const int cr  = (n % 49) * 30 + col;
        float s = 0.f;
#pragma unroll
        for (int k = 0; k < SPLITK; ++k)
            s += partial[(size_t)k * (B_ * CPAD) + (size_t)row * CPAD + cr];
        s += bias[cr];
        sa[t / 30][col] = s;
        if (col >= 10) labels[(size_t)n * 20 + (col - 10)] = s;
    }
    __syncthreads();

    if (t < 8) {
        const int n = base + t;
        const float* a = sa[t];
        float mv = a[10]; int mi = 0;
#pragma unroll
        for (int j = 1; j < 20; ++j) {
            float v = a[10 + j];
            if (v > mv) { mv = v; mi = j; }      // strict > => first-index tie-break
        }
        const float lp = (float)mi;
        const int gx = n % 7, gy = (n / 7) % 7;
        const float cw = 1.0f / 7.0f;
        const float nx = (float)gx * cw, ny = (float)gy * cw;
#pragma unroll
        for (int sl = 0; sl < 2; ++sl) {
            const int off = 5 * sl;
            const float bx0 = a[off], bx1 = a[off + 1];
            const float w_ = a[off + 2], h_ = a[off + 3];
            const float sc = a[off + 5];         // faithful port quirk: off+5
            const float cx = bx0 * cw + nx, cy = bx1 * cw + ny;
            const float X1 = cx - 0.5f * w_, Y1 = cy - 0.5f * h_;
            const float X2 = cx + 0.5f * w_, Y2 = cy + 0.5f * h_;
            const int m = sl * NCELL + n;
            boxes[m * 4 + 0] = X1 - 0.5f * X2;
            boxes[m * 4 + 1] = Y1 - 0.5f * Y2;
            boxes[m * 4 + 2] = X1 + 0.5f * X2;
            boxes[m * 4 + 3] = Y1 + 0.5f * Y2;
            scores[m] = sc;
            valid[m] = (sc * lp > 0.5f) ? 1 : 0;
        }
    }
}

// ---------------------------------------------------------------------------
// Inverted greedy NMS + direct write of the (few) picked output rows.
// One 1024-thread block per slot. LDS SoA staging (~75 KB); alive set =
// 4 bits/thread register bitmask; 2 barriers per pick; no atomics.
// Output was pre-zeroed by gemm_splitk, so ONLY picked rows are written:
// O(picks) stores + O(picks*20) label gathers — legal narrow-phase work.
// ---------------------------------------------------------------------------
__global__ __launch_bounds__(NMS_T) void nms_pick(
    const float* __restrict__ boxes, const float* __restrict__ scores,
    const int* __restrict__ valid, const float* __restrict__ labels,
    float* __restrict__ out)
{
    __shared__ float sX1[NCELL], sY1[NCELL], sX2[NCELL], sY2[NCELL];
    __shared__ float sSc[NCELL];
    __shared__ int   pickList[NCELL];
    __shared__ float rv[16];
    __shared__ int   rn[16];
    __shared__ int   pickN, npicks;

    const int slot = blockIdx.x;
    const int base = slot * NCELL;
    const int t = threadIdx.x;

    if (t == 0) npicks = 0;
    unsigned am = 0;                     // alive bitmask for my <=4 entries
#pragma unroll
    for (int q = 0; q < QMAX; ++q) {
        const int n = t + q * NMS_T;
        if (n < NCELL) {
            const float4 bb = *(const float4*)&boxes[(size_t)(base + n) * 4];
            sX1[n] = bb.x; sY1[n] = bb.y; sX2[n] = bb.z; sY2[n] = bb.w;
            sSc[n] = scores[base + n];
            if (valid[base + n]) am |= 1u << q;
        }
    }
    __syncthreads();

    for (;;) {
        // ---- argmax over alive: (score desc, index asc) ----
        float bv = -1e30f; int bn = 0x7fffffff;
#pragma unroll
        for (int q = 0; q < QMAX; ++q)
            if ((am >> q) & 1u) {
                const int n = t + q * NMS_T;
                const float v = sSc[n];
                if (v > bv || (v == bv && n < bn)) { bv = v; bn = n; }
            }
#pragma unroll
        for (int o = 32; o > 0; o >>= 1) {
            const float ov = __shfl_down(bv, o);
            const int   on = __shfl_down(bn, o);
            if (ov > bv || (ov == bv && on < bn)) { bv = ov; bn = on; }
        }
        if ((t & 63) == 0) { rv[t >> 6] = bv; rn[t >> 6] = bn; }
        __syncthreads();
        if (t == 0) {
            float v2 = rv[0]; int n2 = rn[0];
#pragma unroll
            for (int q = 1; q < 16; ++q)
                if (rv[q] > v2 || (rv[q] == v2 && rn[q] < n2)) { v2 = rv[q]; n2 = rn[q]; }
            if (v2 == -1e30f) { pickN = -1; }
            else { pickN = n2; pickList[npicks++] = n2; }
        }
        __syncthreads();
        const int pn = pickN;
        if (pn < 0) break;
        const float px1 = sX1[pn], py1 = sY1[pn], px2 = sX2[pn], py2 = sY2[pn];
        const float pa = (px2 - px1) * (py2 - py1);

        // ---- retain only entries with IoU >= 0.5 vs pick (and not pick) ----
#pragma unroll
        for (int q = 0; q < QMAX; ++q)
            if ((am >> q) & 1u) {
                const int n = t + q * NMS_T;
                const float x1 = sX1[n], y1 = sY1[n], x2 = sX2[n], y2 = sY2[n];
                const float an = (x2 - x1) * (y2 - y1);
                const float ix1 = fmaxf(x1, px1), iy1 = fmaxf(y1, py1);
                const float ix2 = fminf(x2, px2), iy2 = fminf(y2, py2);
                const float inter = fmaxf(ix2 - ix1, 0.f) * fmaxf(iy2 - iy1, 0.f);
                const float iou = inter / (pa + an - inter);   // IEEE divide
                if (!(iou >= 0.5f) || n == pn) am &= ~(1u << q);
            }
        // next iteration's barriers order rv/pick reuse
    }

    // ---- write ONLY the picked rows: [boxes*448, score, labels(20)] ----
    const int np = npicks;
    for (int u = t; u < np * 25; u += NMS_T) {
        const int pi = u / 25;
        const int c  = u % 25;
        const int n  = pickList[pi];
        float v;
        if (c < 4)       v = (c == 0 ? sX1[n] : c == 1 ? sY1[n] : c == 2 ? sX2[n] : sY2[n]) * 448.0f;
        else if (c == 4) v = sSc[n];
        else             v = labels[(size_t)n * 20 + (c - 5)];
        out[(size_t)(base + n) * 25 + c] = v;
    }
}

// ---------------------------------------------------------------------------
extern "C" void kernel_launch(void* const* d_in, const int* in_sizes, int n_in,
                              void* d_out, int out_size, void* d_ws, size_t ws_size,
                              hipStream_t stream)
{
    const float* x = (const float*)d_in[0];
    const float* W = (const float*)d_in[1];
    const float* b = (const float*)d_in[2];
    float* out = (float*)d_out;

    float* ws      = (float*)d_ws;
    float* partial = ws;                                        // 16*64*1536
    float* labels  = partial + (size_t)SPLITK * B_ * CPAD;      // 3136*20
    float* boxes   = labels + (size_t)NCELL * 20;               // 3136*8
    float* scores  = boxes + (size_t)NCELL * 8;                 // 3136*2
    int*   valid   = (int*)(scores + (size_t)NCELL * 2);        // 3136*2

    hipLaunchKernelGGL(gemm_splitk, dim3(16, SPLITK), dim3(256), 0, stream,
                       x, W, partial, out);
    hipLaunchKernelGGL(combine_prep, dim3(NCELL / 8), dim3(256), 0, stream,
                       partial, b, labels, boxes, scores, valid);
    hipLaunchKernelGGL(nms_pick, dim3(2), dim3(NMS_T), 0, stream,
                       boxes, scores, valid, labels, out);
}